// Round 11
// baseline (810.576 us; speedup 1.0000x reference)
//
#include <hip/hip_runtime.h>
#include <cmath>

#define D_MODEL 1024
#define D_STATE 16
#define D_INNER 2048
#define NB 4
#define SEQL 2048
#define ROWS (NB*SEQL)        // 8192
#define XZ_LD (2*D_INNER)     // 4096

typedef __attribute__((ext_vector_type(8))) short short8;
typedef __attribute__((ext_vector_type(4))) float f32x4;

__device__ __forceinline__ float sigmoidf_(float v) { return 1.0f / (1.0f + __expf(-v)); }

__device__ __forceinline__ unsigned short bf16rne(float f) {
    unsigned u = __float_as_uint(f);
    unsigned r = (u + 0x7FFFu + ((u >> 16) & 1u)) >> 16;
    return (unsigned short)r;
}

// ---------------- fp32 -> [hi | lo] bf16 split, row-packed ----------------
__global__ __launch_bounds__(256) void pack2_k(const float4* __restrict__ in,
    ushort4* __restrict__ out, int l2K4, int n4)
{
    int i = blockIdx.x * 256 + threadIdx.x;
    if (i >= n4) return;
    int K4 = 1 << l2K4;
    int r = i >> l2K4, c = i & (K4 - 1);
    float4 v = in[i];
    ushort4 h, l;
    h.x = bf16rne(v.x); l.x = bf16rne(v.x - __uint_as_float((unsigned)h.x << 16));
    h.y = bf16rne(v.y); l.y = bf16rne(v.y - __uint_as_float((unsigned)h.y << 16));
    h.z = bf16rne(v.z); l.z = bf16rne(v.z - __uint_as_float((unsigned)h.z << 16));
    h.w = bf16rne(v.w); l.w = bf16rne(v.w - __uint_as_float((unsigned)h.w << 16));
    size_t base = (size_t)r * 2 * K4 + c;
    out[base] = h;
    out[base + K4] = l;
}

// ======== deep-ring bf16x3 NT GEMM: BM x 256 tile, 4-panel ring, 1 barrier/slice ========
// A2: M rows [hi(K)|lo(K)] pitch lda; B2: N rows [hi|lo] pitch ldb. K' = 3K slices of 32:
// slice s pairs A{hi,lo,hi} x B{hi,hi,lo} -> hh + lh + hl (refcheck'd rounds 8-10).
// 8 waves (2m x 4n); BM=256: per-wave 128x64 (32 MFMA + 12 ds_read_b128 / slice);
// BM=128: per-wave 64x64 (16 MFMA + 8 ds_read). LDS k-slot-major [4 slots][rows][8]:
// linear for global_load_lds, conflict-free 256B-stripe ds_read_b128 (0 conflicts r4-r10).
// RING (depth 3): during slice t stage panel t+3 -> a panel has ~3 slices (~1500 cy) in
// flight, covering HBM-miss latency. ONE barrier + ONE counted vmcnt per slice:
//   BAR(t):  s_waitcnt vmcnt(2L)  [L = GLDS/stage; leaves stages t+1,t+2 in flight,
//            drains stage(t) issued 3 slices ago]  ->  s_barrier
//   body:    stage(t+3) -> 12 ds_read -> setprio(1) -> 32 MFMA -> setprio(0)
// Overwrite ledger: stage(t+3) targets panel (t-1)&3; every wave's slice t-1 ds_reads
// retired before its MFMAs (compiler lgkmcnt) hence before BAR(t). Tail: 2L -> L -> 0.
#define GLDS(gp, lp) __builtin_amdgcn_global_load_lds( \
    (const __attribute__((address_space(1))) void*)(gp), \
    (__attribute__((address_space(3))) void*)(lp), 16, 0, 0)

extern __shared__ __align__(16) unsigned short smemD[];

template<int BM>
__global__ __launch_bounds__(512, 2) void gemmD(
    const unsigned short* __restrict__ A2, int lda,
    const unsigned short* __restrict__ B2, int ldb,
    float* __restrict__ C, int ldc, int K)
{
    constexpr int APAN = BM * 32;              // ushorts per A panel
    constexpr int BPAN = 256 * 32;
    constexpr int LA   = BM / 128;             // A GLDS per thread per stage
    constexpr int LTOT = LA + 2;               // GLDS per thread per stage
    constexpr int WROW = BM / 2;               // per-wave M rows
    constexpr int MF   = WROW / 16;            // A frags per wave
    unsigned short* sA = smemD;                // 4 * APAN
    unsigned short* sB = smemD + 4 * APAN;     // 4 * BPAN

    const int tid = threadIdx.x;
    const int bm = blockIdx.y * BM, bn = blockIdx.x * 256;
    const int wave = tid >> 6, lane = tid & 63;
    const int wm = wave >> 2, wn = wave & 3;
    const int fr = lane & 15, kq = lane >> 4;
    const int NS = K >> 5, NT = 3 * NS;

    size_t offA[LA], offB[2];
#pragma unroll
    for (int i = 0; i < LA; ++i) {
        int c = i * 512 + tid;
        int row = c & (BM - 1), slot = (BM == 256) ? (c >> 8) : (c >> 7);
        offA[i] = (size_t)(bm + row) * lda + slot * 8;
    }
#pragma unroll
    for (int i = 0; i < 2; ++i) {
        int c = i * 512 + tid;
        int row = c & 255, slot = c >> 8;
        offB[i] = (size_t)(bn + row) * ldb + slot * 8;
    }

    auto stage = [&](int s) {
        int ka = (s < NS) ? s * 32 : (s < 2 * NS) ? K + (s - NS) * 32 : (s - 2 * NS) * 32;
        int kb = (s < NS) ? s * 32 : (s < 2 * NS) ? (s - NS) * 32 : K + (s - 2 * NS) * 32;
        unsigned short* dA = sA + (s & 3) * APAN;
        unsigned short* dB = sB + (s & 3) * BPAN;
#pragma unroll
        for (int i = 0; i < LA; ++i)
            GLDS(A2 + offA[i] + ka, dA + (i * 512 + tid) * 8);
#pragma unroll
        for (int i = 0; i < 2; ++i)
            GLDS(B2 + offB[i] + kb, dB + (i * 512 + tid) * 8);
    };

    f32x4 acc[MF][4];
#pragma unroll
    for (int m = 0; m < MF; ++m)
#pragma unroll
        for (int n = 0; n < 4; ++n) acc[m][n] = (f32x4){0.f, 0.f, 0.f, 0.f};

    // prologue: 3 panels in flight
    stage(0); stage(1); stage(2);

    for (int t = 0; t < NT; ++t) {
        if (t + 2 < NT)      asm volatile("s_waitcnt vmcnt(%0)" :: "i"(2 * LTOT) : "memory");
        else if (t + 1 < NT) asm volatile("s_waitcnt vmcnt(%0)" :: "i"(LTOT) : "memory");
        else                 asm volatile("s_waitcnt vmcnt(0)" ::: "memory");
        __builtin_amdgcn_s_barrier();
        asm volatile("" ::: "memory");

        if (t + 3 < NT) stage(t + 3);

        const unsigned short* pA = sA + (t & 3) * APAN;
        const unsigned short* pB = sB + (t & 3) * BPAN;
        short8 a[MF], b[4];
#pragma unroll
        for (int m = 0; m < MF; ++m)
            a[m] = *(const short8*)&pA[(kq * BM + wm * WROW + m * 16 + fr) * 8];
#pragma unroll
        for (int n = 0; n < 4; ++n)
            b[n] = *(const short8*)&pB[(kq * 256 + wn * 64 + n * 16 + fr) * 8];

        __builtin_amdgcn_s_setprio(1);
#pragma unroll
        for (int m = 0; m < MF; ++m)
#pragma unroll
            for (int n = 0; n < 4; ++n)
                acc[m][n] = __builtin_amdgcn_mfma_f32_16x16x32_bf16(a[m], b[n], acc[m][n], 0, 0, 0);
        __builtin_amdgcn_s_setprio(0);
    }

    // C/D layout: col = lane&15, row = (lane>>4)*4 + j
#pragma unroll
    for (int m = 0; m < MF; ++m) {
        int row0 = bm + wm * WROW + m * 16 + kq * 4;
#pragma unroll
        for (int j = 0; j < 4; ++j) {
            float* Cr = C + (size_t)(row0 + j) * ldc + bn + wn * 64 + fr;
#pragma unroll
            for (int n = 0; n < 4; ++n) Cr[n * 16] = acc[m][n][j];
        }
    }
}

// ---------------- causal depthwise conv (D_CONV=4) + SiLU ----------------
__global__ __launch_bounds__(256) void conv_silu_k(
    const float* __restrict__ xz, const float* __restrict__ conv_w,
    const float* __restrict__ conv_b, float* __restrict__ x_conv)
{
    int idx = blockIdx.x * 256 + threadIdx.x;   // ROWS * 512 total
    int q = idx & 511;
    int r = idx >> 9;
    int b = r >> 11, t = r & (SEQL - 1);
    int d0 = q << 2;
    float w[4][4];
#pragma unroll
    for (int c = 0; c < 4; ++c) *(float4*)w[c] = *(const float4*)&conv_w[(d0 + c) * 4];
    float4 acc = *(const float4*)&conv_b[d0];
    const float* xp = xz + (size_t)(b * SEQL) * XZ_LD + d0;
#pragma unroll
    for (int k = 0; k < 4; ++k) {
        int t2 = t - 3 + k;
        if (t2 >= 0) {
            float4 v = *(const float4*)(xp + (size_t)t2 * XZ_LD);
            acc.x = fmaf(v.x, w[0][k], acc.x);
            acc.y = fmaf(v.y, w[1][k], acc.y);
            acc.z = fmaf(v.z, w[2][k], acc.z);
            acc.w = fmaf(v.w, w[3][k], acc.w);
        }
    }
    acc.x *= sigmoidf_(acc.x);
    acc.y *= sigmoidf_(acc.y);
    acc.z *= sigmoidf_(acc.z);
    acc.w *= sigmoidf_(acc.w);
    *(float4*)&x_conv[(size_t)r * D_INNER + d0] = acc;
}

// ---------------- x_proj: 33 dots of length 2048 per row -> A_bar/B_bar/C ----------------
__global__ __launch_bounds__(256) void proj_k(
    const float* __restrict__ x_conv, const float* __restrict__ W_xproj,
    const float* __restrict__ A_log,
    float* __restrict__ Abar, float* __restrict__ Bbar, float* __restrict__ Cmat)
{
    __shared__ float sdbl[4][33];
    int tid = threadIdx.x;
    int w = tid >> 6, lane = tid & 63;
    int row = blockIdx.x * 4 + w;
    const float* xrow = x_conv + (size_t)row * D_INNER;
    float4 xr[8];
#pragma unroll
    for (int it = 0; it < 8; ++it)
        xr[it] = *(const float4*)&xrow[it * 256 + lane * 4];

    for (int j = 0; j < 33; ++j) {
        const float* wrow = W_xproj + j * D_INNER;
        float accv = 0.f;
#pragma unroll
        for (int it = 0; it < 8; ++it) {
            float4 wv = *(const float4*)&wrow[it * 256 + lane * 4];
            accv = fmaf(xr[it].x, wv.x, accv);
            accv = fmaf(xr[it].y, wv.y, accv);
            accv = fmaf(xr[it].z, wv.z, accv);
            accv = fmaf(xr[it].w, wv.w, accv);
        }
#pragma unroll
        for (int off = 32; off; off >>= 1) accv += __shfl_xor(accv, off);
        if (lane == 0) sdbl[w][j] = accv;
    }
    __syncthreads();
    if (tid < 64) {
        int w2 = tid >> 4, s = tid & 15;
        int row2 = blockIdx.x * 4 + w2;
        float draw = sdbl[w2][32];
        float sp = (draw > 20.f) ? draw : log1pf(__expf(draw));
        float dt = fminf(fmaxf(sp, 0.001f), 0.1f);
        float Aa = -__expf(A_log[s]);
        float dtA = fminf(fmaxf(dt * Aa, -20.f), 0.f);
        Abar[row2 * 16 + s] = __expf(dtA);
        float bb = dt * sdbl[w2][s];
        Bbar[row2 * 16 + s] = fminf(fmaxf(bb, -10.f), 10.f);
        Cmat[row2 * 16 + s] = sdbl[w2][16 + s];
    }
}

// ---------------- SSM scan: 1 state per lane, 16 lanes per channel ----------------
// Emits y as [hi | lo] bf16 into the dead x_proj half of each xz row
// (yh at ushort offset r*2*XZ_LD + d, yl at + D_INNER) -> GEMM2 A operand directly.
#define SCH 16
#define TT 16
__global__ __launch_bounds__(256) void scan_k(
    const float* __restrict__ x_conv, const float* __restrict__ xz,
    unsigned short* __restrict__ yhl,
    const float* __restrict__ Abar, const float* __restrict__ Bbar,
    const float* __restrict__ Cmat, const float* __restrict__ D_param)
{
    __shared__ __align__(16) float sXa[2][SCH][TT];        // [ch][t]
    __shared__ float sZp[2][SCH][TT + 1];
    __shared__ __align__(16) float sPa[2][16][20];         // [s][t], pad 20
    __shared__ __align__(16) float sPb[2][16][20];
    __shared__ __align__(16) float sPc[2][16][20];
    __shared__ __align__(16) float sT[SCH][328];           // [ch][t*20 + s]

    const int tid = threadIdx.x;
    const int b = blockIdx.y, dbase = blockIdx.x * SCH;
    const int chl = tid >> 4, s = tid & 15;
    const float* xc = x_conv + (size_t)(b * SEQL) * D_INNER + dbase;
    const float* zp = xz + (size_t)(b * SEQL) * XZ_LD + D_INNER + dbase;
    const int pbase0 = (b * SEQL) * 16;
    const int st = tid >> 4, sc = tid & 15;

    auto stage = [&](int buf, int tc) {
        int t0 = tc * TT;
        sXa[buf][sc][st] = xc[(size_t)(t0 + st) * D_INNER + sc];
        sZp[buf][sc][st] = zp[(size_t)(t0 + st) * XZ_LD + sc];
        int g = pbase0 + t0 * 16 + tid;
        sPa[buf][sc][st] = Abar[g];
        sPb[buf][sc][st] = Bbar[g];
        sPc[buf][sc][st] = Cmat[g];
    };

    stage(0, 0);
    float h = 0.f;
    const float Dp = D_param[dbase + chl];

    for (int tc = 0; tc < SEQL / TT; ++tc) {
        int buf = tc & 1;
        __syncthreads();
        if (tc + 1 < SEQL / TT) stage(buf ^ 1, tc + 1);

        float p[16];
#pragma unroll
        for (int q = 0; q < 4; ++q) {
            float4 a4 = *(const float4*)&sPa[buf][s][q * 4];
            float4 b4 = *(const float4*)&sPb[buf][s][q * 4];
            float4 c4 = *(const float4*)&sPc[buf][s][q * 4];
            float4 x4 = *(const float4*)&sXa[buf][chl][q * 4];
            h = fminf(fmaxf(fmaf(b4.x, x4.x, a4.x * h), -100.f), 100.f); p[q * 4 + 0] = h * c4.x;
            h = fminf(fmaxf(fmaf(b4.y, x4.y, a4.y * h), -100.f), 100.f); p[q * 4 + 1] = h * c4.y;
            h = fminf(fmaxf(fmaf(b4.z, x4.z, a4.z * h), -100.f), 100.f); p[q * 4 + 2] = h * c4.z;
            h = fminf(fmaxf(fmaf(b4.w, x4.w, a4.w * h), -100.f), 100.f); p[q * 4 + 3] = h * c4.w;
        }
#pragma unroll
        for (int i = 0; i < 16; ++i) sT[chl][i * 20 + s] = p[i];
        float4 r0 = *(const float4*)&sT[chl][s * 20 + 0];
        float4 r1 = *(const float4*)&sT[chl][s * 20 + 4];
        float4 r2 = *(const float4*)&sT[chl][s * 20 + 8];
        float4 r3 = *(const float4*)&sT[chl][s * 20 + 12];
        float ysum = ((r0.x + r1.x + r2.x + r3.x) + (r0.y + r1.y + r2.y + r3.y))
                   + ((r0.z + r1.z + r2.z + r3.z) + (r0.w + r1.w + r2.w + r3.w));
        float z = sZp[buf][chl][s];
        float x = sXa[buf][chl][s];
        float o = fmaf(x, Dp, ysum * (z * sigmoidf_(z)));
        size_t r = (size_t)(b * SEQL + tc * TT + s);
        unsigned short hb = bf16rne(o);
        yhl[r * 2 * XZ_LD + dbase + chl] = hb;
        yhl[r * 2 * XZ_LD + D_INNER + dbase + chl] =
            bf16rne(o - __uint_as_float((unsigned)hb << 16));
    }
}

extern "C" void kernel_launch(void* const* d_in, const int* in_sizes, int n_in,
                              void* d_out, int out_size, void* d_ws, size_t ws_size,
                              hipStream_t stream) {
    const float* x       = (const float*)d_in[0];
    const float* W_in    = (const float*)d_in[1];
    const float* conv_w  = (const float*)d_in[2];
    const float* conv_b  = (const float*)d_in[3];
    const float* W_xproj = (const float*)d_in[4];
    const float* A_log   = (const float*)d_in[5];
    const float* D_param = (const float*)d_in[6];
    const float* W_out   = (const float*)d_in[7];
    float* out = (float*)d_out;

    // ---- workspace: round-1 footprint (202.9 MB), phase-aliased ----
    char* p = (char*)d_ws;
    char* xzB = p;
    float* xz = (float*)xzB;                 // 134.2 MB; rows: [x_proj | z] fp32
    p += (size_t)ROWS * XZ_LD * 4;
    char* xcB = p;
    float* x_conv = (float*)xcB;             // 67.1 MB
    p += (size_t)ROWS * D_INNER * 4;
    float* Abar = (float*)p; p += (size_t)ROWS * 16 * 4;
    float* Bbar = (float*)p; p += (size_t)ROWS * 16 * 4;
    float* Cm   = (float*)p; p += (size_t)ROWS * 16 * 4;

    // phase-0 aliases in x_conv region: x2 (8192x2048) + Wi2 (4096x2048) bf16 = 50.3 MB
    unsigned short* x2  = (unsigned short*)xcB;
    unsigned short* Wi2 = x2 + (size_t)ROWS * 2 * D_MODEL;
    // phase-4 alias in x_conv region (after scan consumed x_conv): Wo2 (1024x4096) = 8.4 MB
    unsigned short* Wo2 = (unsigned short*)xcB;
    // scan writes yh/yl into the x_proj half of xz rows (pitch 2*XZ_LD ushorts)
    unsigned short* yhl = (unsigned short*)xzB;

    constexpr int SM1 = (4 * 256 * 32 + 4 * 256 * 32) * 2;   // 128 KiB
    constexpr int SM2 = (4 * 128 * 32 + 4 * 256 * 32) * 2;   // 96 KiB

    // 0) pack x, W_in -> [hi | lo]
    pack2_k<<<ROWS * D_MODEL / 4 / 256, 256, 0, stream>>>(
        (const float4*)x, (ushort4*)x2, 8, ROWS * D_MODEL / 4);
    pack2_k<<<2 * D_INNER * D_MODEL / 4 / 256, 256, 0, stream>>>(
        (const float4*)W_in, (ushort4*)Wi2, 8, 2 * D_INNER * D_MODEL / 4);
    // 1) xz = x @ W_in^T  (M=8192, N=4096, K=1024); grid (16, 32), 512 blocks
    gemmD<256><<<dim3(4096 / 256, ROWS / 256), 512, SM1, stream>>>(
        x2, 2 * D_MODEL, Wi2, 2 * D_MODEL, xz, XZ_LD, D_MODEL);
    // 2) conv + silu (reads xz x_proj half, overwrites phase-0 aliases with x_conv)
    conv_silu_k<<<ROWS * 512 / 256, 256, 0, stream>>>(xz, conv_w, conv_b, x_conv);
    // 3) x_proj
    proj_k<<<ROWS / 4, 256, 0, stream>>>(x_conv, W_xproj, A_log, Abar, Bbar, Cm);
    // 4) scan -> yh/yl bf16 into xz rows' first half
    scan_k<<<dim3(D_INNER / SCH, NB), 256, 0, stream>>>(
        x_conv, xz, yhl, Abar, Bbar, Cm, D_param);
    // 5) pack W_out -> [hi | lo] into the now-dead x_conv region
    pack2_k<<<D_MODEL * D_INNER / 4 / 256, 256, 0, stream>>>(
        (const float4*)W_out, (ushort4*)Wo2, 9, D_MODEL * D_INNER / 4);
    // 6) out = y @ W_out^T  (M=8192, N=1024, K=2048); A = packed yhl, pitch 2*XZ_LD;
    //    grid (4, 64) = 256 blocks, full chip
    gemmD<128><<<dim3(1024 / 256, ROWS / 128), 512, SM2, stream>>>(
        yhl, 2 * XZ_LD, Wo2, 2 * D_INNER, out, D_MODEL, D_INNER);
}

// Round 12
// 698.443 us; speedup vs baseline: 1.1605x; 1.1605x over previous
//
#include <hip/hip_runtime.h>
#include <cmath>

#define D_MODEL 1024
#define D_STATE 16
#define D_INNER 2048
#define NB 4
#define SEQL 2048
#define ROWS (NB*SEQL)        // 8192
#define XZ_LD (2*D_INNER)     // 4096

typedef __attribute__((ext_vector_type(8))) short short8;
typedef __attribute__((ext_vector_type(4))) float f32x4;

__device__ __forceinline__ float sigmoidf_(float v) { return 1.0f / (1.0f + __expf(-v)); }

__device__ __forceinline__ unsigned short bf16rne(float f) {
    unsigned u = __float_as_uint(f);
    unsigned r = (u + 0x7FFFu + ((u >> 16) & 1u)) >> 16;
    return (unsigned short)r;
}

// ---------------- fp32 -> [hi | lo] bf16 split, row-packed ----------------
__global__ __launch_bounds__(256) void pack2_k(const float4* __restrict__ in,
    ushort4* __restrict__ out, int l2K4, int n4)
{
    int i = blockIdx.x * 256 + threadIdx.x;
    if (i >= n4) return;
    int K4 = 1 << l2K4;
    int r = i >> l2K4, c = i & (K4 - 1);
    float4 v = in[i];
    ushort4 h, l;
    h.x = bf16rne(v.x); l.x = bf16rne(v.x - __uint_as_float((unsigned)h.x << 16));
    h.y = bf16rne(v.y); l.y = bf16rne(v.y - __uint_as_float((unsigned)h.y << 16));
    h.z = bf16rne(v.z); l.z = bf16rne(v.z - __uint_as_float((unsigned)h.z << 16));
    h.w = bf16rne(v.w); l.w = bf16rne(v.w - __uint_as_float((unsigned)h.w << 16));
    size_t base = (size_t)r * 2 * K4 + c;
    out[base] = h;
    out[base + K4] = l;
}

// ============ 8-phase-style split-bf16 NT GEMM (round-10 structure, verbatim) ============
// A2: M rows [hi(K)|lo(K)] pitch lda; B2: N rows [hi|lo] pitch ldb. K' = terms*K slices
// of 32: terms=3 -> hh + lh + hl; terms=2 -> hh + lh = fp32(A) x bf16(B).
// 8 waves (2m x 4n). BM=256: per-wave 128x64, 2 phases/slice; BM=128: 1 phase/slice.
// Per phase: {ds_read frags || stage -> barrier -> setprio(1) -> 16 MFMA -> setprio(0)
// -> barrier}. LDS k-slot-major [4 slots][rows][8]: linear for global_load_lds,
// conflict-free 256B-stripe ds_read_b128 (0 conflicts rounds 4-11).
// Ring of 3 panels; counted vmcnt at slice end confirms panel t+1, barrier makes it
// visible to all waves (measured best schedule: 744 TF GEMM1, round 10).
#define GLDS(gp, lp) __builtin_amdgcn_global_load_lds( \
    (const __attribute__((address_space(1))) void*)(gp), \
    (__attribute__((address_space(3))) void*)(lp), 16, 0, 0)

extern __shared__ __align__(16) unsigned short smem8[];

template<int BM>
__global__ __launch_bounds__(512, 2) void gemm8p(
    const unsigned short* __restrict__ A2, int lda,
    const unsigned short* __restrict__ B2, int ldb,
    float* __restrict__ C, int ldc, int K, int terms)
{
    constexpr int APAN = BM * 32;          // ushorts per A panel
    constexpr int BPAN = 256 * 32;
    constexpr int LA   = BM / 128;         // A gload_lds instrs per stage (2 or 1)
    constexpr int MH   = BM / 128;         // phases per slice
    constexpr int WROW = (BM == 256) ? 128 : 64;   // per-wave M rows
    unsigned short* sA = smem8;
    unsigned short* sB = smem8 + 3 * APAN;

    const int tid = threadIdx.x;
    const int bm = blockIdx.y * BM, bn = blockIdx.x * 256;
    const int wave = tid >> 6, lane = tid & 63;
    const int wm = wave >> 2, wn = wave & 3;
    const int fr = lane & 15, kq = lane >> 4;
    const int NS = K >> 5, NT = terms * NS;

    // per-thread staging address offsets (elem units); LDS dest is linear: c*8
    size_t offA[LA], offB[2];
#pragma unroll
    for (int i = 0; i < LA; ++i) {
        int c = i * 512 + tid;
        int row = c & (BM - 1), slot = (BM == 256) ? (c >> 8) : (c >> 7);
        offA[i] = (size_t)(bm + row) * lda + slot * 8;
    }
#pragma unroll
    for (int i = 0; i < 2; ++i) {
        int c = i * 512 + tid;
        int row = c & 255, slot = c >> 8;
        offB[i] = (size_t)(bn + row) * ldb + slot * 8;
    }

    auto stageA = [&](int s) {
        int ka = (s < NS) ? s * 32 : (s < 2 * NS) ? K + (s - NS) * 32 : (s - 2 * NS) * 32;
        unsigned short* d = sA + (s % 3) * APAN;
#pragma unroll
        for (int i = 0; i < LA; ++i)
            GLDS(A2 + offA[i] + ka, d + (i * 512 + tid) * 8);
    };
    auto stageB = [&](int s) {
        int kb = (s < NS) ? s * 32 : (s < 2 * NS) ? (s - NS) * 32 : K + (s - 2 * NS) * 32;
        unsigned short* d = sB + (s % 3) * BPAN;
#pragma unroll
        for (int i = 0; i < 2; ++i)
            GLDS(B2 + offB[i] + kb, d + (i * 512 + tid) * 8);
    };

    f32x4 acc[4 * MH][4];
#pragma unroll
    for (int m = 0; m < 4 * MH; ++m)
#pragma unroll
        for (int n = 0; n < 4; ++n) acc[m][n] = (f32x4){0.f, 0.f, 0.f, 0.f};

    // prologue: panels 0,1 staged; confirm panel 0 (own), then barrier -> all waves
    stageA(0); stageB(0); stageA(1); stageB(1);
    if constexpr (BM == 256) asm volatile("s_waitcnt vmcnt(4)" ::: "memory");
    else                     asm volatile("s_waitcnt vmcnt(3)" ::: "memory");
    __builtin_amdgcn_s_barrier();
    asm volatile("" ::: "memory");

    for (int t = 0; t < NT; ++t) {
        const unsigned short* pA = sA + (t % 3) * APAN;
        const unsigned short* pB = sB + (t % 3) * BPAN;
        // ---- phase 0: B frags + A m-half 0; stage A(t+2) ----
        short8 b0[4], a0[4];
#pragma unroll
        for (int n = 0; n < 4; ++n)
            b0[n] = *(const short8*)&pB[(kq * 256 + wn * 64 + n * 16 + fr) * 8];
#pragma unroll
        for (int m = 0; m < 4; ++m)
            a0[m] = *(const short8*)&pA[(kq * BM + wm * WROW + m * 16 + fr) * 8];
        if (t + 2 < NT) stageA(t + 2);
        if constexpr (MH == 1) { if (t + 2 < NT) stageB(t + 2); }
        __builtin_amdgcn_s_barrier();
        asm volatile("" ::: "memory");
        __builtin_amdgcn_s_setprio(1);
#pragma unroll
        for (int m = 0; m < 4; ++m)
#pragma unroll
            for (int n = 0; n < 4; ++n)
                acc[m][n] = __builtin_amdgcn_mfma_f32_16x16x32_bf16(a0[m], b0[n], acc[m][n], 0, 0, 0);
        __builtin_amdgcn_s_setprio(0);
        if constexpr (MH == 2) {
            __builtin_amdgcn_s_barrier();
            asm volatile("" ::: "memory");
            // ---- phase 1: A m-half 1 (B reused in regs); stage B(t+2) ----
            short8 a1[4];
#pragma unroll
            for (int m = 0; m < 4; ++m)
                a1[m] = *(const short8*)&pA[(kq * 256 + wm * 128 + 64 + m * 16 + fr) * 8];
            if (t + 2 < NT) stageB(t + 2);
            __builtin_amdgcn_s_barrier();
            asm volatile("" ::: "memory");
            __builtin_amdgcn_s_setprio(1);
#pragma unroll
            for (int m = 0; m < 4; ++m)
#pragma unroll
                for (int n = 0; n < 4; ++n)
                    acc[4 + m][n] = __builtin_amdgcn_mfma_f32_16x16x32_bf16(a1[m], b0[n], acc[4 + m][n], 0, 0, 0);
            __builtin_amdgcn_s_setprio(0);
        }
        // end-of-slice: confirm own share of panel t+1 landed; barrier -> all waves
        if (t + 2 < NT) {
            if constexpr (BM == 256) asm volatile("s_waitcnt vmcnt(4)" ::: "memory");
            else                     asm volatile("s_waitcnt vmcnt(3)" ::: "memory");
        } else if (t + 1 < NT) {
            asm volatile("s_waitcnt vmcnt(0)" ::: "memory");
        }
        __builtin_amdgcn_s_barrier();
        asm volatile("" ::: "memory");
    }

    // C/D layout: col = lane&15, row = (lane>>4)*4 + j
#pragma unroll
    for (int mm = 0; mm < 4 * MH; ++mm) {
        int row0 = bm + wm * WROW + mm * 16 + kq * 4;
#pragma unroll
        for (int j = 0; j < 4; ++j) {
            float* Cr = C + (size_t)(row0 + j) * ldc + bn + wn * 64 + fr;
#pragma unroll
            for (int n = 0; n < 4; ++n) Cr[n * 16] = acc[mm][n][j];
        }
    }
}

// ---------------- causal depthwise conv (D_CONV=4) + SiLU ----------------
__global__ __launch_bounds__(256) void conv_silu_k(
    const float* __restrict__ xz, const float* __restrict__ conv_w,
    const float* __restrict__ conv_b, float* __restrict__ x_conv)
{
    int idx = blockIdx.x * 256 + threadIdx.x;   // ROWS * 512 total
    int q = idx & 511;
    int r = idx >> 9;
    int b = r >> 11, t = r & (SEQL - 1);
    int d0 = q << 2;
    float w[4][4];
#pragma unroll
    for (int c = 0; c < 4; ++c) *(float4*)w[c] = *(const float4*)&conv_w[(d0 + c) * 4];
    float4 acc = *(const float4*)&conv_b[d0];
    const float* xp = xz + (size_t)(b * SEQL) * XZ_LD + d0;
#pragma unroll
    for (int k = 0; k < 4; ++k) {
        int t2 = t - 3 + k;
        if (t2 >= 0) {
            float4 v = *(const float4*)(xp + (size_t)t2 * XZ_LD);
            acc.x = fmaf(v.x, w[0][k], acc.x);
            acc.y = fmaf(v.y, w[1][k], acc.y);
            acc.z = fmaf(v.z, w[2][k], acc.z);
            acc.w = fmaf(v.w, w[3][k], acc.w);
        }
    }
    acc.x *= sigmoidf_(acc.x);
    acc.y *= sigmoidf_(acc.y);
    acc.z *= sigmoidf_(acc.z);
    acc.w *= sigmoidf_(acc.w);
    *(float4*)&x_conv[(size_t)r * D_INNER + d0] = acc;
}

// ---------------- x_proj: 33 dots of length 2048 per row -> A_bar/B_bar/C ----------------
__global__ __launch_bounds__(256) void proj_k(
    const float* __restrict__ x_conv, const float* __restrict__ W_xproj,
    const float* __restrict__ A_log,
    float* __restrict__ Abar, float* __restrict__ Bbar, float* __restrict__ Cmat)
{
    __shared__ float sdbl[4][33];
    int tid = threadIdx.x;
    int w = tid >> 6, lane = tid & 63;
    int row = blockIdx.x * 4 + w;
    const float* xrow = x_conv + (size_t)row * D_INNER;
    float4 xr[8];
#pragma unroll
    for (int it = 0; it < 8; ++it)
        xr[it] = *(const float4*)&xrow[it * 256 + lane * 4];

    for (int j = 0; j < 33; ++j) {
        const float* wrow = W_xproj + j * D_INNER;
        float accv = 0.f;
#pragma unroll
        for (int it = 0; it < 8; ++it) {
            float4 wv = *(const float4*)&wrow[it * 256 + lane * 4];
            accv = fmaf(xr[it].x, wv.x, accv);
            accv = fmaf(xr[it].y, wv.y, accv);
            accv = fmaf(xr[it].z, wv.z, accv);
            accv = fmaf(xr[it].w, wv.w, accv);
        }
#pragma unroll
        for (int off = 32; off; off >>= 1) accv += __shfl_xor(accv, off);
        if (lane == 0) sdbl[w][j] = accv;
    }
    __syncthreads();
    if (tid < 64) {
        int w2 = tid >> 4, s = tid & 15;
        int row2 = blockIdx.x * 4 + w2;
        float draw = sdbl[w2][32];
        float sp = (draw > 20.f) ? draw : log1pf(__expf(draw));
        float dt = fminf(fmaxf(sp, 0.001f), 0.1f);
        float Aa = -__expf(A_log[s]);
        float dtA = fminf(fmaxf(dt * Aa, -20.f), 0.f);
        Abar[row2 * 16 + s] = __expf(dtA);
        float bb = dt * sdbl[w2][s];
        Bbar[row2 * 16 + s] = fminf(fmaxf(bb, -10.f), 10.f);
        Cmat[row2 * 16 + s] = sdbl[w2][16 + s];
    }
}

// ---------------- SSM scan: 1 state per lane, 16 lanes per channel ----------------
// Emits y as [hi | lo] bf16 into the dead x_proj half of each xz row
// (yh at ushort offset r*2*XZ_LD + d, yl at + D_INNER) -> GEMM2 A operand directly.
#define SCH 16
#define TT 16
__global__ __launch_bounds__(256) void scan_k(
    const float* __restrict__ x_conv, const float* __restrict__ xz,
    unsigned short* __restrict__ yhl,
    const float* __restrict__ Abar, const float* __restrict__ Bbar,
    const float* __restrict__ Cmat, const float* __restrict__ D_param)
{
    __shared__ __align__(16) float sXa[2][SCH][TT];        // [ch][t]
    __shared__ float sZp[2][SCH][TT + 1];
    __shared__ __align__(16) float sPa[2][16][20];         // [s][t], pad 20
    __shared__ __align__(16) float sPb[2][16][20];
    __shared__ __align__(16) float sPc[2][16][20];
    __shared__ __align__(16) float sT[SCH][328];           // [ch][t*20 + s]

    const int tid = threadIdx.x;
    const int b = blockIdx.y, dbase = blockIdx.x * SCH;
    const int chl = tid >> 4, s = tid & 15;
    const float* xc = x_conv + (size_t)(b * SEQL) * D_INNER + dbase;
    const float* zp = xz + (size_t)(b * SEQL) * XZ_LD + D_INNER + dbase;
    const int pbase0 = (b * SEQL) * 16;
    const int st = tid >> 4, sc = tid & 15;

    auto stage = [&](int buf, int tc) {
        int t0 = tc * TT;
        sXa[buf][sc][st] = xc[(size_t)(t0 + st) * D_INNER + sc];
        sZp[buf][sc][st] = zp[(size_t)(t0 + st) * XZ_LD + sc];
        int g = pbase0 + t0 * 16 + tid;
        sPa[buf][sc][st] = Abar[g];
        sPb[buf][sc][st] = Bbar[g];
        sPc[buf][sc][st] = Cmat[g];
    };

    stage(0, 0);
    float h = 0.f;
    const float Dp = D_param[dbase + chl];

    for (int tc = 0; tc < SEQL / TT; ++tc) {
        int buf = tc & 1;
        __syncthreads();
        if (tc + 1 < SEQL / TT) stage(buf ^ 1, tc + 1);

        float p[16];
#pragma unroll
        for (int q = 0; q < 4; ++q) {
            float4 a4 = *(const float4*)&sPa[buf][s][q * 4];
            float4 b4 = *(const float4*)&sPb[buf][s][q * 4];
            float4 c4 = *(const float4*)&sPc[buf][s][q * 4];
            float4 x4 = *(const float4*)&sXa[buf][chl][q * 4];
            h = fminf(fmaxf(fmaf(b4.x, x4.x, a4.x * h), -100.f), 100.f); p[q * 4 + 0] = h * c4.x;
            h = fminf(fmaxf(fmaf(b4.y, x4.y, a4.y * h), -100.f), 100.f); p[q * 4 + 1] = h * c4.y;
            h = fminf(fmaxf(fmaf(b4.z, x4.z, a4.z * h), -100.f), 100.f); p[q * 4 + 2] = h * c4.z;
            h = fminf(fmaxf(fmaf(b4.w, x4.w, a4.w * h), -100.f), 100.f); p[q * 4 + 3] = h * c4.w;
        }
#pragma unroll
        for (int i = 0; i < 16; ++i) sT[chl][i * 20 + s] = p[i];
        float4 r0 = *(const float4*)&sT[chl][s * 20 + 0];
        float4 r1 = *(const float4*)&sT[chl][s * 20 + 4];
        float4 r2 = *(const float4*)&sT[chl][s * 20 + 8];
        float4 r3 = *(const float4*)&sT[chl][s * 20 + 12];
        float ysum = ((r0.x + r1.x + r2.x + r3.x) + (r0.y + r1.y + r2.y + r3.y))
                   + ((r0.z + r1.z + r2.z + r3.z) + (r0.w + r1.w + r2.w + r3.w));
        float z = sZp[buf][chl][s];
        float x = sXa[buf][chl][s];
        float o = fmaf(x, Dp, ysum * (z * sigmoidf_(z)));
        size_t r = (size_t)(b * SEQL + tc * TT + s);
        unsigned short hb = bf16rne(o);
        yhl[r * 2 * XZ_LD + dbase + chl] = hb;
        yhl[r * 2 * XZ_LD + D_INNER + dbase + chl] =
            bf16rne(o - __uint_as_float((unsigned)hb << 16));
    }
}

extern "C" void kernel_launch(void* const* d_in, const int* in_sizes, int n_in,
                              void* d_out, int out_size, void* d_ws, size_t ws_size,
                              hipStream_t stream) {
    const float* x       = (const float*)d_in[0];
    const float* W_in    = (const float*)d_in[1];
    const float* conv_w  = (const float*)d_in[2];
    const float* conv_b  = (const float*)d_in[3];
    const float* W_xproj = (const float*)d_in[4];
    const float* A_log   = (const float*)d_in[5];
    const float* D_param = (const float*)d_in[6];
    const float* W_out   = (const float*)d_in[7];
    float* out = (float*)d_out;

    // ---- workspace: round-1 footprint (202.9 MB), phase-aliased ----
    char* p = (char*)d_ws;
    char* xzB = p;
    float* xz = (float*)xzB;                 // 134.2 MB; rows: [x_proj | z] fp32
    p += (size_t)ROWS * XZ_LD * 4;
    char* xcB = p;
    float* x_conv = (float*)xcB;             // 67.1 MB
    p += (size_t)ROWS * D_INNER * 4;
    float* Abar = (float*)p; p += (size_t)ROWS * 16 * 4;
    float* Bbar = (float*)p; p += (size_t)ROWS * 16 * 4;
    float* Cm   = (float*)p; p += (size_t)ROWS * 16 * 4;

    // phase-0 aliases in x_conv region: x2 (8192x2048) + Wi2 (4096x2048) bf16 = 50.3 MB
    unsigned short* x2  = (unsigned short*)xcB;
    unsigned short* Wi2 = x2 + (size_t)ROWS * 2 * D_MODEL;
    // phase-4 alias in x_conv region (after scan consumed x_conv): Wo2 (1024x4096) = 8.4 MB
    unsigned short* Wo2 = (unsigned short*)xcB;
    // scan writes yh/yl into the x_proj half of xz rows (pitch 2*XZ_LD ushorts)
    unsigned short* yhl = (unsigned short*)xzB;

    constexpr int SM1 = (3 * 256 * 32 + 3 * 256 * 32) * 2;   // 96 KiB
    constexpr int SM2 = (3 * 128 * 32 + 3 * 256 * 32) * 2;   // 72 KiB

    // 0) pack x, W_in -> [hi | lo]
    pack2_k<<<ROWS * D_MODEL / 4 / 256, 256, 0, stream>>>(
        (const float4*)x, (ushort4*)x2, 8, ROWS * D_MODEL / 4);
    pack2_k<<<2 * D_INNER * D_MODEL / 4 / 256, 256, 0, stream>>>(
        (const float4*)W_in, (ushort4*)Wi2, 8, 2 * D_INNER * D_MODEL / 4);
    // 1) xz = x @ W_in^T  (M=8192, N=4096, K=1024), 3-term; grid (16, 32), 512 blocks
    gemm8p<256><<<dim3(4096 / 256, ROWS / 256), 512, SM1, stream>>>(
        x2, 2 * D_MODEL, Wi2, 2 * D_MODEL, xz, XZ_LD, D_MODEL, 3);
    // 2) conv + silu (reads xz x_proj half, overwrites phase-0 aliases with x_conv)
    conv_silu_k<<<ROWS * 512 / 256, 256, 0, stream>>>(xz, conv_w, conv_b, x_conv);
    // 3) x_proj
    proj_k<<<ROWS / 4, 256, 0, stream>>>(x_conv, W_xproj, A_log, Abar, Bbar, Cm);
    // 4) scan -> yh/yl bf16 into xz rows' first half
    scan_k<<<dim3(D_INNER / SCH, NB), 256, 0, stream>>>(
        x_conv, xz, yhl, Abar, Bbar, Cm, D_param);
    // 5) pack W_out -> [hi | lo] into the now-dead x_conv region
    pack2_k<<<D_MODEL * D_INNER / 4 / 256, 256, 0, stream>>>(
        (const float4*)W_out, (ushort4*)Wo2, 9, D_MODEL * D_INNER / 4);
    // 6) out = y @ W_out^T  (M=8192, N=1024, K=2048), 2-term (= fp32(y) x bf16(W_out));
    //    A = packed yhl, pitch 2*XZ_LD; grid (4, 64) = 256 blocks
    gemm8p<128><<<dim3(1024 / 256, ROWS / 128), 512, SM2, stream>>>(
        yhl, 2 * XZ_LD, Wo2, 2 * D_INNER, out, D_MODEL, D_INNER, 2);
}

// Round 13
// 607.705 us; speedup vs baseline: 1.3338x; 1.1493x over previous
//
#include <hip/hip_runtime.h>
#include <cmath>

#define D_MODEL 1024
#define D_STATE 16
#define D_INNER 2048
#define NB 4
#define SEQL 2048
#define ROWS (NB*SEQL)        // 8192
#define XZ_LD (2*D_INNER)     // 4096

typedef __attribute__((ext_vector_type(8))) short short8;
typedef __attribute__((ext_vector_type(4))) float f32x4;

__device__ __forceinline__ float sigmoidf_(float v) { return 1.0f / (1.0f + __expf(-v)); }

__device__ __forceinline__ unsigned short bf16rne(float f) {
    unsigned u = __float_as_uint(f);
    unsigned r = (u + 0x7FFFu + ((u >> 16) & 1u)) >> 16;
    return (unsigned short)r;
}

// ---------------- fp32 -> [hi | lo] bf16 split, row-packed ----------------
__global__ __launch_bounds__(256) void pack2_k(const float4* __restrict__ in,
    ushort4* __restrict__ out, int l2K4, int n4)
{
    int i = blockIdx.x * 256 + threadIdx.x;
    if (i >= n4) return;
    int K4 = 1 << l2K4;
    int r = i >> l2K4, c = i & (K4 - 1);
    float4 v = in[i];
    ushort4 h, l;
    h.x = bf16rne(v.x); l.x = bf16rne(v.x - __uint_as_float((unsigned)h.x << 16));
    h.y = bf16rne(v.y); l.y = bf16rne(v.y - __uint_as_float((unsigned)h.y << 16));
    h.z = bf16rne(v.z); l.z = bf16rne(v.z - __uint_as_float((unsigned)h.z << 16));
    h.w = bf16rne(v.w); l.w = bf16rne(v.w - __uint_as_float((unsigned)h.w << 16));
    size_t base = (size_t)r * 2 * K4 + c;
    out[base] = h;
    out[base + K4] = l;
}

// ============ 8-phase-style split-bf16 NT GEMM (round-10 structure, verbatim) ============
// A2: M rows [hi(K)|lo(K)] pitch lda; B2: N rows [hi|lo] pitch ldb. K' = terms*K slices
// of 32: terms=3 -> hh + lh + hl; terms=2 -> hh + lh = fp32(A) x bf16(B).
// 8 waves (2m x 4n). BM=256: per-wave 128x64, 2 phases/slice; BM=128: 1 phase/slice.
// Per phase: {ds_read frags || stage -> barrier -> setprio(1) -> 16 MFMA -> setprio(0)
// -> barrier}. LDS k-slot-major [4 slots][rows][8]: linear for global_load_lds,
// conflict-free 256B-stripe ds_read_b128 (0 conflicts rounds 4-12).
// Ring of 3 panels; counted vmcnt at slice end confirms panel t+1, barrier makes it
// visible to all waves (measured best schedule: 744 TF GEMM1, round 10).
#define GLDS(gp, lp) __builtin_amdgcn_global_load_lds( \
    (const __attribute__((address_space(1))) void*)(gp), \
    (__attribute__((address_space(3))) void*)(lp), 16, 0, 0)

extern __shared__ __align__(16) unsigned short smem8[];

template<int BM>
__global__ __launch_bounds__(512, 2) void gemm8p(
    const unsigned short* __restrict__ A2, int lda,
    const unsigned short* __restrict__ B2, int ldb,
    float* __restrict__ C, int ldc, int K, int terms)
{
    constexpr int APAN = BM * 32;          // ushorts per A panel
    constexpr int BPAN = 256 * 32;
    constexpr int LA   = BM / 128;         // A gload_lds instrs per stage (2 or 1)
    constexpr int MH   = BM / 128;         // phases per slice
    constexpr int WROW = (BM == 256) ? 128 : 64;   // per-wave M rows
    unsigned short* sA = smem8;
    unsigned short* sB = smem8 + 3 * APAN;

    const int tid = threadIdx.x;
    const int bm = blockIdx.y * BM, bn = blockIdx.x * 256;
    const int wave = tid >> 6, lane = tid & 63;
    const int wm = wave >> 2, wn = wave & 3;
    const int fr = lane & 15, kq = lane >> 4;
    const int NS = K >> 5, NT = terms * NS;

    // per-thread staging address offsets (elem units); LDS dest is linear: c*8
    size_t offA[LA], offB[2];
#pragma unroll
    for (int i = 0; i < LA; ++i) {
        int c = i * 512 + tid;
        int row = c & (BM - 1), slot = (BM == 256) ? (c >> 8) : (c >> 7);
        offA[i] = (size_t)(bm + row) * lda + slot * 8;
    }
#pragma unroll
    for (int i = 0; i < 2; ++i) {
        int c = i * 512 + tid;
        int row = c & 255, slot = c >> 8;
        offB[i] = (size_t)(bn + row) * ldb + slot * 8;
    }

    auto stageA = [&](int s) {
        int ka = (s < NS) ? s * 32 : (s < 2 * NS) ? K + (s - NS) * 32 : (s - 2 * NS) * 32;
        unsigned short* d = sA + (s % 3) * APAN;
#pragma unroll
        for (int i = 0; i < LA; ++i)
            GLDS(A2 + offA[i] + ka, d + (i * 512 + tid) * 8);
    };
    auto stageB = [&](int s) {
        int kb = (s < NS) ? s * 32 : (s < 2 * NS) ? (s - NS) * 32 : K + (s - 2 * NS) * 32;
        unsigned short* d = sB + (s % 3) * BPAN;
#pragma unroll
        for (int i = 0; i < 2; ++i)
            GLDS(B2 + offB[i] + kb, d + (i * 512 + tid) * 8);
    };

    f32x4 acc[4 * MH][4];
#pragma unroll
    for (int m = 0; m < 4 * MH; ++m)
#pragma unroll
        for (int n = 0; n < 4; ++n) acc[m][n] = (f32x4){0.f, 0.f, 0.f, 0.f};

    // prologue: panels 0,1 staged; confirm panel 0 (own), then barrier -> all waves
    stageA(0); stageB(0); stageA(1); stageB(1);
    if constexpr (BM == 256) asm volatile("s_waitcnt vmcnt(4)" ::: "memory");
    else                     asm volatile("s_waitcnt vmcnt(3)" ::: "memory");
    __builtin_amdgcn_s_barrier();
    asm volatile("" ::: "memory");

    for (int t = 0; t < NT; ++t) {
        const unsigned short* pA = sA + (t % 3) * APAN;
        const unsigned short* pB = sB + (t % 3) * BPAN;
        // ---- phase 0: B frags + A m-half 0; stage A(t+2) ----
        short8 b0[4], a0[4];
#pragma unroll
        for (int n = 0; n < 4; ++n)
            b0[n] = *(const short8*)&pB[(kq * 256 + wn * 64 + n * 16 + fr) * 8];
#pragma unroll
        for (int m = 0; m < 4; ++m)
            a0[m] = *(const short8*)&pA[(kq * BM + wm * WROW + m * 16 + fr) * 8];
        if (t + 2 < NT) stageA(t + 2);
        if constexpr (MH == 1) { if (t + 2 < NT) stageB(t + 2); }
        __builtin_amdgcn_s_barrier();
        asm volatile("" ::: "memory");
        __builtin_amdgcn_s_setprio(1);
#pragma unroll
        for (int m = 0; m < 4; ++m)
#pragma unroll
            for (int n = 0; n < 4; ++n)
                acc[m][n] = __builtin_amdgcn_mfma_f32_16x16x32_bf16(a0[m], b0[n], acc[m][n], 0, 0, 0);
        __builtin_amdgcn_s_setprio(0);
        if constexpr (MH == 2) {
            __builtin_amdgcn_s_barrier();
            asm volatile("" ::: "memory");
            // ---- phase 1: A m-half 1 (B reused in regs); stage B(t+2) ----
            short8 a1[4];
#pragma unroll
            for (int m = 0; m < 4; ++m)
                a1[m] = *(const short8*)&pA[(kq * 256 + wm * 128 + 64 + m * 16 + fr) * 8];
            if (t + 2 < NT) stageB(t + 2);
            __builtin_amdgcn_s_barrier();
            asm volatile("" ::: "memory");
            __builtin_amdgcn_s_setprio(1);
#pragma unroll
            for (int m = 0; m < 4; ++m)
#pragma unroll
                for (int n = 0; n < 4; ++n)
                    acc[4 + m][n] = __builtin_amdgcn_mfma_f32_16x16x32_bf16(a1[m], b0[n], acc[4 + m][n], 0, 0, 0);
            __builtin_amdgcn_s_setprio(0);
        }
        // end-of-slice: confirm own share of panel t+1 landed; barrier -> all waves
        if (t + 2 < NT) {
            if constexpr (BM == 256) asm volatile("s_waitcnt vmcnt(4)" ::: "memory");
            else                     asm volatile("s_waitcnt vmcnt(3)" ::: "memory");
        } else if (t + 1 < NT) {
            asm volatile("s_waitcnt vmcnt(0)" ::: "memory");
        }
        __builtin_amdgcn_s_barrier();
        asm volatile("" ::: "memory");
    }

    // C/D layout: col = lane&15, row = (lane>>4)*4 + j
#pragma unroll
    for (int mm = 0; mm < 4 * MH; ++mm) {
        int row0 = bm + wm * WROW + mm * 16 + kq * 4;
#pragma unroll
        for (int j = 0; j < 4; ++j) {
            float* Cr = C + (size_t)(row0 + j) * ldc + bn + wn * 64 + fr;
#pragma unroll
            for (int n = 0; n < 4; ++n) Cr[n * 16] = acc[mm][n][j];
        }
    }
}

// ---------------- causal depthwise conv (D_CONV=4) + SiLU ----------------
__global__ __launch_bounds__(256) void conv_silu_k(
    const float* __restrict__ xz, const float* __restrict__ conv_w,
    const float* __restrict__ conv_b, float* __restrict__ x_conv)
{
    int idx = blockIdx.x * 256 + threadIdx.x;   // ROWS * 512 total
    int q = idx & 511;
    int r = idx >> 9;
    int b = r >> 11, t = r & (SEQL - 1);
    int d0 = q << 2;
    float w[4][4];
#pragma unroll
    for (int c = 0; c < 4; ++c) *(float4*)w[c] = *(const float4*)&conv_w[(d0 + c) * 4];
    float4 acc = *(const float4*)&conv_b[d0];
    const float* xp = xz + (size_t)(b * SEQL) * XZ_LD + d0;
#pragma unroll
    for (int k = 0; k < 4; ++k) {
        int t2 = t - 3 + k;
        if (t2 >= 0) {
            float4 v = *(const float4*)(xp + (size_t)t2 * XZ_LD);
            acc.x = fmaf(v.x, w[0][k], acc.x);
            acc.y = fmaf(v.y, w[1][k], acc.y);
            acc.z = fmaf(v.z, w[2][k], acc.z);
            acc.w = fmaf(v.w, w[3][k], acc.w);
        }
    }
    acc.x *= sigmoidf_(acc.x);
    acc.y *= sigmoidf_(acc.y);
    acc.z *= sigmoidf_(acc.z);
    acc.w *= sigmoidf_(acc.w);
    *(float4*)&x_conv[(size_t)r * D_INNER + d0] = acc;
}

// ---------------- x_proj: 33 dots of length 2048 per row -> A_bar/B_bar/C ----------------
__global__ __launch_bounds__(256) void proj_k(
    const float* __restrict__ x_conv, const float* __restrict__ W_xproj,
    const float* __restrict__ A_log,
    float* __restrict__ Abar, float* __restrict__ Bbar, float* __restrict__ Cmat)
{
    __shared__ float sdbl[4][33];
    int tid = threadIdx.x;
    int w = tid >> 6, lane = tid & 63;
    int row = blockIdx.x * 4 + w;
    const float* xrow = x_conv + (size_t)row * D_INNER;
    float4 xr[8];
#pragma unroll
    for (int it = 0; it < 8; ++it)
        xr[it] = *(const float4*)&xrow[it * 256 + lane * 4];

    for (int j = 0; j < 33; ++j) {
        const float* wrow = W_xproj + j * D_INNER;
        float accv = 0.f;
#pragma unroll
        for (int it = 0; it < 8; ++it) {
            float4 wv = *(const float4*)&wrow[it * 256 + lane * 4];
            accv = fmaf(xr[it].x, wv.x, accv);
            accv = fmaf(xr[it].y, wv.y, accv);
            accv = fmaf(xr[it].z, wv.z, accv);
            accv = fmaf(xr[it].w, wv.w, accv);
        }
#pragma unroll
        for (int off = 32; off; off >>= 1) accv += __shfl_xor(accv, off);
        if (lane == 0) sdbl[w][j] = accv;
    }
    __syncthreads();
    if (tid < 64) {
        int w2 = tid >> 4, s = tid & 15;
        int row2 = blockIdx.x * 4 + w2;
        float draw = sdbl[w2][32];
        float sp = (draw > 20.f) ? draw : log1pf(__expf(draw));
        float dt = fminf(fmaxf(sp, 0.001f), 0.1f);
        float Aa = -__expf(A_log[s]);
        float dtA = fminf(fmaxf(dt * Aa, -20.f), 0.f);
        Abar[row2 * 16 + s] = __expf(dtA);
        float bb = dt * sdbl[w2][s];
        Bbar[row2 * 16 + s] = fminf(fmaxf(bb, -10.f), 10.f);
        Cmat[row2 * 16 + s] = sdbl[w2][16 + s];
    }
}

// ---------------- SSM scan: 1 state per lane, 16 lanes per channel ----------------
// Emits y as [hi | lo] bf16 into the dead x_proj half of each xz row
// (yh at ushort offset r*2*XZ_LD + d, yl at + D_INNER) -> GEMM2 A operand directly.
#define SCH 16
#define TT 16
__global__ __launch_bounds__(256) void scan_k(
    const float* __restrict__ x_conv, const float* __restrict__ xz,
    unsigned short* __restrict__ yhl,
    const float* __restrict__ Abar, const float* __restrict__ Bbar,
    const float* __restrict__ Cmat, const float* __restrict__ D_param)
{
    __shared__ __align__(16) float sXa[2][SCH][TT];        // [ch][t]
    __shared__ float sZp[2][SCH][TT + 1];
    __shared__ __align__(16) float sPa[2][16][20];         // [s][t], pad 20
    __shared__ __align__(16) float sPb[2][16][20];
    __shared__ __align__(16) float sPc[2][16][20];
    __shared__ __align__(16) float sT[SCH][328];           // [ch][t*20 + s]

    const int tid = threadIdx.x;
    const int b = blockIdx.y, dbase = blockIdx.x * SCH;
    const int chl = tid >> 4, s = tid & 15;
    const float* xc = x_conv + (size_t)(b * SEQL) * D_INNER + dbase;
    const float* zp = xz + (size_t)(b * SEQL) * XZ_LD + D_INNER + dbase;
    const int pbase0 = (b * SEQL) * 16;
    const int st = tid >> 4, sc = tid & 15;

    auto stage = [&](int buf, int tc) {
        int t0 = tc * TT;
        sXa[buf][sc][st] = xc[(size_t)(t0 + st) * D_INNER + sc];
        sZp[buf][sc][st] = zp[(size_t)(t0 + st) * XZ_LD + sc];
        int g = pbase0 + t0 * 16 + tid;
        sPa[buf][sc][st] = Abar[g];
        sPb[buf][sc][st] = Bbar[g];
        sPc[buf][sc][st] = Cmat[g];
    };

    stage(0, 0);
    float h = 0.f;
    const float Dp = D_param[dbase + chl];

    for (int tc = 0; tc < SEQL / TT; ++tc) {
        int buf = tc & 1;
        __syncthreads();
        if (tc + 1 < SEQL / TT) stage(buf ^ 1, tc + 1);

        float p[16];
#pragma unroll
        for (int q = 0; q < 4; ++q) {
            float4 a4 = *(const float4*)&sPa[buf][s][q * 4];
            float4 b4 = *(const float4*)&sPb[buf][s][q * 4];
            float4 c4 = *(const float4*)&sPc[buf][s][q * 4];
            float4 x4 = *(const float4*)&sXa[buf][chl][q * 4];
            h = fminf(fmaxf(fmaf(b4.x, x4.x, a4.x * h), -100.f), 100.f); p[q * 4 + 0] = h * c4.x;
            h = fminf(fmaxf(fmaf(b4.y, x4.y, a4.y * h), -100.f), 100.f); p[q * 4 + 1] = h * c4.y;
            h = fminf(fmaxf(fmaf(b4.z, x4.z, a4.z * h), -100.f), 100.f); p[q * 4 + 2] = h * c4.z;
            h = fminf(fmaxf(fmaf(b4.w, x4.w, a4.w * h), -100.f), 100.f); p[q * 4 + 3] = h * c4.w;
        }
#pragma unroll
        for (int i = 0; i < 16; ++i) sT[chl][i * 20 + s] = p[i];
        float4 r0 = *(const float4*)&sT[chl][s * 20 + 0];
        float4 r1 = *(const float4*)&sT[chl][s * 20 + 4];
        float4 r2 = *(const float4*)&sT[chl][s * 20 + 8];
        float4 r3 = *(const float4*)&sT[chl][s * 20 + 12];
        float ysum = ((r0.x + r1.x + r2.x + r3.x) + (r0.y + r1.y + r2.y + r3.y))
                   + ((r0.z + r1.z + r2.z + r3.z) + (r0.w + r1.w + r2.w + r3.w));
        float z = sZp[buf][chl][s];
        float x = sXa[buf][chl][s];
        float o = fmaf(x, Dp, ysum * (z * sigmoidf_(z)));
        size_t r = (size_t)(b * SEQL + tc * TT + s);
        unsigned short hb = bf16rne(o);
        yhl[r * 2 * XZ_LD + dbase + chl] = hb;
        yhl[r * 2 * XZ_LD + D_INNER + dbase + chl] =
            bf16rne(o - __uint_as_float((unsigned)hb << 16));
    }
}

extern "C" void kernel_launch(void* const* d_in, const int* in_sizes, int n_in,
                              void* d_out, int out_size, void* d_ws, size_t ws_size,
                              hipStream_t stream) {
    const float* x       = (const float*)d_in[0];
    const float* W_in    = (const float*)d_in[1];
    const float* conv_w  = (const float*)d_in[2];
    const float* conv_b  = (const float*)d_in[3];
    const float* W_xproj = (const float*)d_in[4];
    const float* A_log   = (const float*)d_in[5];
    const float* D_param = (const float*)d_in[6];
    const float* W_out   = (const float*)d_in[7];
    float* out = (float*)d_out;

    // ---- workspace: round-1 footprint (202.9 MB), phase-aliased ----
    char* p = (char*)d_ws;
    char* xzB = p;
    float* xz = (float*)xzB;                 // 134.2 MB; rows: [x_proj | z] fp32
    p += (size_t)ROWS * XZ_LD * 4;
    char* xcB = p;
    float* x_conv = (float*)xcB;             // 67.1 MB
    p += (size_t)ROWS * D_INNER * 4;
    float* Abar = (float*)p; p += (size_t)ROWS * 16 * 4;
    float* Bbar = (float*)p; p += (size_t)ROWS * 16 * 4;
    float* Cm   = (float*)p; p += (size_t)ROWS * 16 * 4;

    // phase-0 aliases in x_conv region: x2 (8192x2048) + Wi2 (4096x2048) bf16 = 50.3 MB
    unsigned short* x2  = (unsigned short*)xcB;
    unsigned short* Wi2 = x2 + (size_t)ROWS * 2 * D_MODEL;
    // phase-4 alias in x_conv region (after scan consumed x_conv): Wo2 (1024x4096) = 8.4 MB
    unsigned short* Wo2 = (unsigned short*)xcB;
    // scan writes yh/yl into the x_proj half of xz rows (pitch 2*XZ_LD ushorts)
    unsigned short* yhl = (unsigned short*)xzB;

    constexpr int SM1 = (3 * 256 * 32 + 3 * 256 * 32) * 2;   // 96 KiB
    constexpr int SM2 = (3 * 128 * 32 + 3 * 256 * 32) * 2;   // 72 KiB

    // 0) pack x, W_in -> [hi | lo]
    pack2_k<<<ROWS * D_MODEL / 4 / 256, 256, 0, stream>>>(
        (const float4*)x, (ushort4*)x2, 8, ROWS * D_MODEL / 4);
    pack2_k<<<2 * D_INNER * D_MODEL / 4 / 256, 256, 0, stream>>>(
        (const float4*)W_in, (ushort4*)Wi2, 8, 2 * D_INNER * D_MODEL / 4);
    // 1) xz = x @ W_in^T  (M=8192, N=4096, K=1024), 2-term (= fp32(x) x bf16(W_in));
    //    grid (16, 32), 512 blocks
    gemm8p<256><<<dim3(4096 / 256, ROWS / 256), 512, SM1, stream>>>(
        x2, 2 * D_MODEL, Wi2, 2 * D_MODEL, xz, XZ_LD, D_MODEL, 2);
    // 2) conv + silu (reads xz x_proj half, overwrites phase-0 aliases with x_conv)
    conv_silu_k<<<ROWS * 512 / 256, 256, 0, stream>>>(xz, conv_w, conv_b, x_conv);
    // 3) x_proj
    proj_k<<<ROWS / 4, 256, 0, stream>>>(x_conv, W_xproj, A_log, Abar, Bbar, Cm);
    // 4) scan -> yh/yl bf16 into xz rows' first half
    scan_k<<<dim3(D_INNER / SCH, NB), 256, 0, stream>>>(
        x_conv, xz, yhl, Abar, Bbar, Cm, D_param);
    // 5) pack W_out -> [hi | lo] into the now-dead x_conv region
    pack2_k<<<D_MODEL * D_INNER / 4 / 256, 256, 0, stream>>>(
        (const float4*)W_out, (ushort4*)Wo2, 9, D_MODEL * D_INNER / 4);
    // 6) out = y @ W_out^T  (M=8192, N=1024, K=2048), 2-term (= fp32(y) x bf16(W_out));
    //    A = packed yhl, pitch 2*XZ_LD; grid (4, 64) = 256 blocks
    gemm8p<128><<<dim3(1024 / 256, ROWS / 128), 512, SM2, stream>>>(
        yhl, 2 * XZ_LD, Wo2, 2 * D_INNER, out, D_MODEL, D_INNER, 2);
}

// Round 14
// 495.547 us; speedup vs baseline: 1.6357x; 1.2263x over previous
//
#include <hip/hip_runtime.h>
#include <cmath>

#define D_MODEL 1024
#define D_STATE 16
#define D_INNER 2048
#define NB 4
#define SEQL 2048
#define ROWS (NB*SEQL)        // 8192
#define XZ_LD (2*D_INNER)     // 4096

typedef __attribute__((ext_vector_type(8))) short short8;
typedef __attribute__((ext_vector_type(4))) float f32x4;

__device__ __forceinline__ float sigmoidf_(float v) { return 1.0f / (1.0f + __expf(-v)); }

__device__ __forceinline__ unsigned short bf16rne(float f) {
    unsigned u = __float_as_uint(f);
    unsigned r = (u + 0x7FFFu + ((u >> 16) & 1u)) >> 16;
    return (unsigned short)r;
}

// ---------------- fp32 -> [hi | lo] bf16 split, row-packed ----------------
__global__ __launch_bounds__(256) void pack2_k(const float4* __restrict__ in,
    ushort4* __restrict__ out, int l2K4, int n4)
{
    int i = blockIdx.x * 256 + threadIdx.x;
    if (i >= n4) return;
    int K4 = 1 << l2K4;
    int r = i >> l2K4, c = i & (K4 - 1);
    float4 v = in[i];
    ushort4 h, l;
    h.x = bf16rne(v.x); l.x = bf16rne(v.x - __uint_as_float((unsigned)h.x << 16));
    h.y = bf16rne(v.y); l.y = bf16rne(v.y - __uint_as_float((unsigned)h.y << 16));
    h.z = bf16rne(v.z); l.z = bf16rne(v.z - __uint_as_float((unsigned)h.z << 16));
    h.w = bf16rne(v.w); l.w = bf16rne(v.w - __uint_as_float((unsigned)h.w << 16));
    size_t base = (size_t)r * 2 * K4 + c;
    out[base] = h;
    out[base + K4] = l;
}

// ============ 8-phase-style split-bf16 NT GEMM (round-10 structure, verbatim) ============
// A2: M rows [hi(K)|lo(K)] pitch lda; B2: N rows [hi|lo] pitch ldb. K' = terms*K slices
// of 32: terms=3 -> hh + lh + hl; terms=2 -> hh + lh; terms=1 -> hh (pure bf16).
// 8 waves (2m x 4n). BM=256: per-wave 128x64, 2 phases/slice; BM=128: 1 phase/slice.
// Per phase: {ds_read frags || stage -> barrier -> setprio(1) -> 16 MFMA -> setprio(0)
// -> barrier}. LDS k-slot-major [4 slots][rows][8]: linear for global_load_lds,
// conflict-free 256B-stripe ds_read_b128 (0 conflicts rounds 4-13).
// Ring of 3 panels; counted vmcnt at slice end confirms panel t+1, barrier makes it
// visible to all waves (measured best schedule: 744 TF effective, round 10).
#define GLDS(gp, lp) __builtin_amdgcn_global_load_lds( \
    (const __attribute__((address_space(1))) void*)(gp), \
    (__attribute__((address_space(3))) void*)(lp), 16, 0, 0)

extern __shared__ __align__(16) unsigned short smem8[];

template<int BM>
__global__ __launch_bounds__(512, 2) void gemm8p(
    const unsigned short* __restrict__ A2, int lda,
    const unsigned short* __restrict__ B2, int ldb,
    float* __restrict__ C, int ldc, int K, int terms)
{
    constexpr int APAN = BM * 32;          // ushorts per A panel
    constexpr int BPAN = 256 * 32;
    constexpr int LA   = BM / 128;         // A gload_lds instrs per stage (2 or 1)
    constexpr int MH   = BM / 128;         // phases per slice
    constexpr int WROW = (BM == 256) ? 128 : 64;   // per-wave M rows
    unsigned short* sA = smem8;
    unsigned short* sB = smem8 + 3 * APAN;

    const int tid = threadIdx.x;
    const int bm = blockIdx.y * BM, bn = blockIdx.x * 256;
    const int wave = tid >> 6, lane = tid & 63;
    const int wm = wave >> 2, wn = wave & 3;
    const int fr = lane & 15, kq = lane >> 4;
    const int NS = K >> 5, NT = terms * NS;

    // per-thread staging address offsets (elem units); LDS dest is linear: c*8
    size_t offA[LA], offB[2];
#pragma unroll
    for (int i = 0; i < LA; ++i) {
        int c = i * 512 + tid;
        int row = c & (BM - 1), slot = (BM == 256) ? (c >> 8) : (c >> 7);
        offA[i] = (size_t)(bm + row) * lda + slot * 8;
    }
#pragma unroll
    for (int i = 0; i < 2; ++i) {
        int c = i * 512 + tid;
        int row = c & 255, slot = c >> 8;
        offB[i] = (size_t)(bn + row) * ldb + slot * 8;
    }

    auto stageA = [&](int s) {
        int ka = (s < NS) ? s * 32 : (s < 2 * NS) ? K + (s - NS) * 32 : (s - 2 * NS) * 32;
        unsigned short* d = sA + (s % 3) * APAN;
#pragma unroll
        for (int i = 0; i < LA; ++i)
            GLDS(A2 + offA[i] + ka, d + (i * 512 + tid) * 8);
    };
    auto stageB = [&](int s) {
        int kb = (s < NS) ? s * 32 : (s < 2 * NS) ? (s - NS) * 32 : K + (s - 2 * NS) * 32;
        unsigned short* d = sB + (s % 3) * BPAN;
#pragma unroll
        for (int i = 0; i < 2; ++i)
            GLDS(B2 + offB[i] + kb, d + (i * 512 + tid) * 8);
    };

    f32x4 acc[4 * MH][4];
#pragma unroll
    for (int m = 0; m < 4 * MH; ++m)
#pragma unroll
        for (int n = 0; n < 4; ++n) acc[m][n] = (f32x4){0.f, 0.f, 0.f, 0.f};

    // prologue: panels 0,1 staged; confirm panel 0 (own), then barrier -> all waves
    stageA(0); stageB(0); stageA(1); stageB(1);
    if constexpr (BM == 256) asm volatile("s_waitcnt vmcnt(4)" ::: "memory");
    else                     asm volatile("s_waitcnt vmcnt(3)" ::: "memory");
    __builtin_amdgcn_s_barrier();
    asm volatile("" ::: "memory");

    for (int t = 0; t < NT; ++t) {
        const unsigned short* pA = sA + (t % 3) * APAN;
        const unsigned short* pB = sB + (t % 3) * BPAN;
        // ---- phase 0: B frags + A m-half 0; stage A(t+2) ----
        short8 b0[4], a0[4];
#pragma unroll
        for (int n = 0; n < 4; ++n)
            b0[n] = *(const short8*)&pB[(kq * 256 + wn * 64 + n * 16 + fr) * 8];
#pragma unroll
        for (int m = 0; m < 4; ++m)
            a0[m] = *(const short8*)&pA[(kq * BM + wm * WROW + m * 16 + fr) * 8];
        if (t + 2 < NT) stageA(t + 2);
        if constexpr (MH == 1) { if (t + 2 < NT) stageB(t + 2); }
        __builtin_amdgcn_s_barrier();
        asm volatile("" ::: "memory");
        __builtin_amdgcn_s_setprio(1);
#pragma unroll
        for (int m = 0; m < 4; ++m)
#pragma unroll
            for (int n = 0; n < 4; ++n)
                acc[m][n] = __builtin_amdgcn_mfma_f32_16x16x32_bf16(a0[m], b0[n], acc[m][n], 0, 0, 0);
        __builtin_amdgcn_s_setprio(0);
        if constexpr (MH == 2) {
            __builtin_amdgcn_s_barrier();
            asm volatile("" ::: "memory");
            // ---- phase 1: A m-half 1 (B reused in regs); stage B(t+2) ----
            short8 a1[4];
#pragma unroll
            for (int m = 0; m < 4; ++m)
                a1[m] = *(const short8*)&pA[(kq * 256 + wm * 128 + 64 + m * 16 + fr) * 8];
            if (t + 2 < NT) stageB(t + 2);
            __builtin_amdgcn_s_barrier();
            asm volatile("" ::: "memory");
            __builtin_amdgcn_s_setprio(1);
#pragma unroll
            for (int m = 0; m < 4; ++m)
#pragma unroll
                for (int n = 0; n < 4; ++n)
                    acc[4 + m][n] = __builtin_amdgcn_mfma_f32_16x16x32_bf16(a1[m], b0[n], acc[4 + m][n], 0, 0, 0);
            __builtin_amdgcn_s_setprio(0);
        }
        // end-of-slice: confirm own share of panel t+1 landed; barrier -> all waves
        if (t + 2 < NT) {
            if constexpr (BM == 256) asm volatile("s_waitcnt vmcnt(4)" ::: "memory");
            else                     asm volatile("s_waitcnt vmcnt(3)" ::: "memory");
        } else if (t + 1 < NT) {
            asm volatile("s_waitcnt vmcnt(0)" ::: "memory");
        }
        __builtin_amdgcn_s_barrier();
        asm volatile("" ::: "memory");
    }

    // C/D layout: col = lane&15, row = (lane>>4)*4 + j
#pragma unroll
    for (int mm = 0; mm < 4 * MH; ++mm) {
        int row0 = bm + wm * WROW + mm * 16 + kq * 4;
#pragma unroll
        for (int j = 0; j < 4; ++j) {
            float* Cr = C + (size_t)(row0 + j) * ldc + bn + wn * 64 + fr;
#pragma unroll
            for (int n = 0; n < 4; ++n) Cr[n * 16] = acc[mm][n][j];
        }
    }
}

// ---------------- causal depthwise conv (D_CONV=4) + SiLU ----------------
__global__ __launch_bounds__(256) void conv_silu_k(
    const float* __restrict__ xz, const float* __restrict__ conv_w,
    const float* __restrict__ conv_b, float* __restrict__ x_conv)
{
    int idx = blockIdx.x * 256 + threadIdx.x;   // ROWS * 512 total
    int q = idx & 511;
    int r = idx >> 9;
    int b = r >> 11, t = r & (SEQL - 1);
    int d0 = q << 2;
    float w[4][4];
#pragma unroll
    for (int c = 0; c < 4; ++c) *(float4*)w[c] = *(const float4*)&conv_w[(d0 + c) * 4];
    float4 acc = *(const float4*)&conv_b[d0];
    const float* xp = xz + (size_t)(b * SEQL) * XZ_LD + d0;
#pragma unroll
    for (int k = 0; k < 4; ++k) {
        int t2 = t - 3 + k;
        if (t2 >= 0) {
            float4 v = *(const float4*)(xp + (size_t)t2 * XZ_LD);
            acc.x = fmaf(v.x, w[0][k], acc.x);
            acc.y = fmaf(v.y, w[1][k], acc.y);
            acc.z = fmaf(v.z, w[2][k], acc.z);
            acc.w = fmaf(v.w, w[3][k], acc.w);
        }
    }
    acc.x *= sigmoidf_(acc.x);
    acc.y *= sigmoidf_(acc.y);
    acc.z *= sigmoidf_(acc.z);
    acc.w *= sigmoidf_(acc.w);
    *(float4*)&x_conv[(size_t)r * D_INNER + d0] = acc;
}

// ---------------- x_proj: 33 dots of length 2048 per row -> A_bar/B_bar/C ----------------
__global__ __launch_bounds__(256) void proj_k(
    const float* __restrict__ x_conv, const float* __restrict__ W_xproj,
    const float* __restrict__ A_log,
    float* __restrict__ Abar, float* __restrict__ Bbar, float* __restrict__ Cmat)
{
    __shared__ float sdbl[4][33];
    int tid = threadIdx.x;
    int w = tid >> 6, lane = tid & 63;
    int row = blockIdx.x * 4 + w;
    const float* xrow = x_conv + (size_t)row * D_INNER;
    float4 xr[8];
#pragma unroll
    for (int it = 0; it < 8; ++it)
        xr[it] = *(const float4*)&xrow[it * 256 + lane * 4];

    for (int j = 0; j < 33; ++j) {
        const float* wrow = W_xproj + j * D_INNER;
        float accv = 0.f;
#pragma unroll
        for (int it = 0; it < 8; ++it) {
            float4 wv = *(const float4*)&wrow[it * 256 + lane * 4];
            accv = fmaf(xr[it].x, wv.x, accv);
            accv = fmaf(xr[it].y, wv.y, accv);
            accv = fmaf(xr[it].z, wv.z, accv);
            accv = fmaf(xr[it].w, wv.w, accv);
        }
#pragma unroll
        for (int off = 32; off; off >>= 1) accv += __shfl_xor(accv, off);
        if (lane == 0) sdbl[w][j] = accv;
    }
    __syncthreads();
    if (tid < 64) {
        int w2 = tid >> 4, s = tid & 15;
        int row2 = blockIdx.x * 4 + w2;
        float draw = sdbl[w2][32];
        float sp = (draw > 20.f) ? draw : log1pf(__expf(draw));
        float dt = fminf(fmaxf(sp, 0.001f), 0.1f);
        float Aa = -__expf(A_log[s]);
        float dtA = fminf(fmaxf(dt * Aa, -20.f), 0.f);
        Abar[row2 * 16 + s] = __expf(dtA);
        float bb = dt * sdbl[w2][s];
        Bbar[row2 * 16 + s] = fminf(fmaxf(bb, -10.f), 10.f);
        Cmat[row2 * 16 + s] = sdbl[w2][16 + s];
    }
}

// ---------------- SSM scan: 1 state per lane, 16 lanes per channel ----------------
// Emits y as [hi | lo] bf16 into the dead x_proj half of each xz row
// (yh at ushort offset r*2*XZ_LD + d, yl at + D_INNER) -> GEMM2 A operand directly.
#define SCH 16
#define TT 16
__global__ __launch_bounds__(256) void scan_k(
    const float* __restrict__ x_conv, const float* __restrict__ xz,
    unsigned short* __restrict__ yhl,
    const float* __restrict__ Abar, const float* __restrict__ Bbar,
    const float* __restrict__ Cmat, const float* __restrict__ D_param)
{
    __shared__ __align__(16) float sXa[2][SCH][TT];        // [ch][t]
    __shared__ float sZp[2][SCH][TT + 1];
    __shared__ __align__(16) float sPa[2][16][20];         // [s][t], pad 20
    __shared__ __align__(16) float sPb[2][16][20];
    __shared__ __align__(16) float sPc[2][16][20];
    __shared__ __align__(16) float sT[SCH][328];           // [ch][t*20 + s]

    const int tid = threadIdx.x;
    const int b = blockIdx.y, dbase = blockIdx.x * SCH;
    const int chl = tid >> 4, s = tid & 15;
    const float* xc = x_conv + (size_t)(b * SEQL) * D_INNER + dbase;
    const float* zp = xz + (size_t)(b * SEQL) * XZ_LD + D_INNER + dbase;
    const int pbase0 = (b * SEQL) * 16;
    const int st = tid >> 4, sc = tid & 15;

    auto stage = [&](int buf, int tc) {
        int t0 = tc * TT;
        sXa[buf][sc][st] = xc[(size_t)(t0 + st) * D_INNER + sc];
        sZp[buf][sc][st] = zp[(size_t)(t0 + st) * XZ_LD + sc];
        int g = pbase0 + t0 * 16 + tid;
        sPa[buf][sc][st] = Abar[g];
        sPb[buf][sc][st] = Bbar[g];
        sPc[buf][sc][st] = Cmat[g];
    };

    stage(0, 0);
    float h = 0.f;
    const float Dp = D_param[dbase + chl];

    for (int tc = 0; tc < SEQL / TT; ++tc) {
        int buf = tc & 1;
        __syncthreads();
        if (tc + 1 < SEQL / TT) stage(buf ^ 1, tc + 1);

        float p[16];
#pragma unroll
        for (int q = 0; q < 4; ++q) {
            float4 a4 = *(const float4*)&sPa[buf][s][q * 4];
            float4 b4 = *(const float4*)&sPb[buf][s][q * 4];
            float4 c4 = *(const float4*)&sPc[buf][s][q * 4];
            float4 x4 = *(const float4*)&sXa[buf][chl][q * 4];
            h = fminf(fmaxf(fmaf(b4.x, x4.x, a4.x * h), -100.f), 100.f); p[q * 4 + 0] = h * c4.x;
            h = fminf(fmaxf(fmaf(b4.y, x4.y, a4.y * h), -100.f), 100.f); p[q * 4 + 1] = h * c4.y;
            h = fminf(fmaxf(fmaf(b4.z, x4.z, a4.z * h), -100.f), 100.f); p[q * 4 + 2] = h * c4.z;
            h = fminf(fmaxf(fmaf(b4.w, x4.w, a4.w * h), -100.f), 100.f); p[q * 4 + 3] = h * c4.w;
        }
#pragma unroll
        for (int i = 0; i < 16; ++i) sT[chl][i * 20 + s] = p[i];
        float4 r0 = *(const float4*)&sT[chl][s * 20 + 0];
        float4 r1 = *(const float4*)&sT[chl][s * 20 + 4];
        float4 r2 = *(const float4*)&sT[chl][s * 20 + 8];
        float4 r3 = *(const float4*)&sT[chl][s * 20 + 12];
        float ysum = ((r0.x + r1.x + r2.x + r3.x) + (r0.y + r1.y + r2.y + r3.y))
                   + ((r0.z + r1.z + r2.z + r3.z) + (r0.w + r1.w + r2.w + r3.w));
        float z = sZp[buf][chl][s];
        float x = sXa[buf][chl][s];
        float o = fmaf(x, Dp, ysum * (z * sigmoidf_(z)));
        size_t r = (size_t)(b * SEQL + tc * TT + s);
        unsigned short hb = bf16rne(o);
        yhl[r * 2 * XZ_LD + dbase + chl] = hb;
        yhl[r * 2 * XZ_LD + D_INNER + dbase + chl] =
            bf16rne(o - __uint_as_float((unsigned)hb << 16));
    }
}

extern "C" void kernel_launch(void* const* d_in, const int* in_sizes, int n_in,
                              void* d_out, int out_size, void* d_ws, size_t ws_size,
                              hipStream_t stream) {
    const float* x       = (const float*)d_in[0];
    const float* W_in    = (const float*)d_in[1];
    const float* conv_w  = (const float*)d_in[2];
    const float* conv_b  = (const float*)d_in[3];
    const float* W_xproj = (const float*)d_in[4];
    const float* A_log   = (const float*)d_in[5];
    const float* D_param = (const float*)d_in[6];
    const float* W_out   = (const float*)d_in[7];
    float* out = (float*)d_out;

    // ---- workspace: round-1 footprint (202.9 MB), phase-aliased ----
    char* p = (char*)d_ws;
    char* xzB = p;
    float* xz = (float*)xzB;                 // 134.2 MB; rows: [x_proj | z] fp32
    p += (size_t)ROWS * XZ_LD * 4;
    char* xcB = p;
    float* x_conv = (float*)xcB;             // 67.1 MB
    p += (size_t)ROWS * D_INNER * 4;
    float* Abar = (float*)p; p += (size_t)ROWS * 16 * 4;
    float* Bbar = (float*)p; p += (size_t)ROWS * 16 * 4;
    float* Cm   = (float*)p; p += (size_t)ROWS * 16 * 4;

    // phase-0 aliases in x_conv region: x2 (8192x2048) + Wi2 (4096x2048) bf16 = 50.3 MB
    unsigned short* x2  = (unsigned short*)xcB;
    unsigned short* Wi2 = x2 + (size_t)ROWS * 2 * D_MODEL;
    // phase-4 alias in x_conv region (after scan consumed x_conv): Wo2 (1024x4096) = 8.4 MB
    unsigned short* Wo2 = (unsigned short*)xcB;
    // scan writes yh/yl into the x_proj half of xz rows (pitch 2*XZ_LD ushorts)
    unsigned short* yhl = (unsigned short*)xzB;

    constexpr int SM1 = (3 * 256 * 32 + 3 * 256 * 32) * 2;   // 96 KiB
    constexpr int SM2 = (3 * 128 * 32 + 3 * 256 * 32) * 2;   // 72 KiB

    // 0) pack x, W_in -> [hi | lo]
    pack2_k<<<ROWS * D_MODEL / 4 / 256, 256, 0, stream>>>(
        (const float4*)x, (ushort4*)x2, 8, ROWS * D_MODEL / 4);
    pack2_k<<<2 * D_INNER * D_MODEL / 4 / 256, 256, 0, stream>>>(
        (const float4*)W_in, (ushort4*)Wi2, 8, 2 * D_INNER * D_MODEL / 4);
    // 1) xz = x @ W_in^T  (M=8192, N=4096, K=1024), 1-term (bf16 x bf16);
    //    grid (16, 32), 512 blocks
    gemm8p<256><<<dim3(4096 / 256, ROWS / 256), 512, SM1, stream>>>(
        x2, 2 * D_MODEL, Wi2, 2 * D_MODEL, xz, XZ_LD, D_MODEL, 1);
    // 2) conv + silu (reads xz x_proj half, overwrites phase-0 aliases with x_conv)
    conv_silu_k<<<ROWS * 512 / 256, 256, 0, stream>>>(xz, conv_w, conv_b, x_conv);
    // 3) x_proj
    proj_k<<<ROWS / 4, 256, 0, stream>>>(x_conv, W_xproj, A_log, Abar, Bbar, Cm);
    // 4) scan -> yh/yl bf16 into xz rows' first half
    scan_k<<<dim3(D_INNER / SCH, NB), 256, 0, stream>>>(
        x_conv, xz, yhl, Abar, Bbar, Cm, D_param);
    // 5) pack W_out -> [hi | lo] into the now-dead x_conv region
    pack2_k<<<D_MODEL * D_INNER / 4 / 256, 256, 0, stream>>>(
        (const float4*)W_out, (ushort4*)Wo2, 9, D_MODEL * D_INNER / 4);
    // 6) out = y @ W_out^T  (M=8192, N=1024, K=2048), 1-term (bf16 y x bf16 W_out);
    //    A = packed yhl, pitch 2*XZ_LD; grid (4, 64) = 256 blocks
    gemm8p<128><<<dim3(1024 / 256, ROWS / 128), 512, SM2, stream>>>(
        yhl, 2 * XZ_LD, Wo2, 2 * D_INNER, out, D_MODEL, D_INNER, 1);
}